// Round 2
// baseline (1013.599 us; speedup 1.0000x reference)
//
#include <hip/hip_runtime.h>

// LoRA multi-head attention forward, B=2 S=2048 D=2048 H=16 dk=128 rank=8.
// Device dtype auto-detected (bf16 vs fp32) -> flag in ws; internal compute bf16.
// Pipeline: detect -> [prep effW^T -> GEMM] x3 (Q,K,V) -> V transpose ->
// causal flash attention -> prep effWo^T -> output GEMM.
// Workspace: 72 MiB + 256 B (W slot reused; Ob aliases Vb).

#define B_   2
#define S_   2048
#define D_   2048
#define H_   16
#define DK_  128
#define MROWS (B_*S_)            // 4096
#define SCALE_ 0.08838834764831845f   // 1/sqrt(128)

using f32x4 = __attribute__((ext_vector_type(4))) float;
using s16x8 = __attribute__((ext_vector_type(8))) short;
typedef unsigned short u16;

__device__ __forceinline__ float b2f(u16 u){ union{unsigned u32; float f;} x; x.u32=((unsigned)u)<<16; return x.f; }
__device__ __forceinline__ u16 f2b(float f){ union{float f; unsigned u;} x; x.f=f; unsigned r=x.u+0x7fffu+((x.u>>16)&1u); return (u16)(r>>16); }

__device__ __forceinline__ void glds16(const void* g, void* l){
  __builtin_amdgcn_global_load_lds((const __attribute__((address_space(1))) unsigned int*)g,
                                   (__attribute__((address_space(3))) unsigned int*)l, 16, 0, 0);
}

// ---------------------------------------------------------------------------
// dtype detector: bf16 N(0,1) data never has bf16-exponent >= 0x90 in either
// half of a u32; fp32 data's low mantissa half does ~44% of the time.
__global__ void detect32(const unsigned* __restrict__ q, int* __restrict__ flag)
{
  __shared__ int s[4];
  int c = 0;
  for (int i = threadIdx.x; i < 4096; i += 256){
    unsigned u = q[i];
    unsigned e0 = (u >> 7) & 0xFFu;      // exponent field of low bf16 half
    if (e0 >= 0x90u) ++c;
  }
  #pragma unroll
  for (int off = 32; off; off >>= 1) c += __shfl_down(c, off);
  if ((threadIdx.x & 63) == 0) s[threadIdx.x >> 6] = c;
  __syncthreads();
  if (threadIdx.x == 0) *flag = ((s[0]+s[1]+s[2]+s[3]) > 64) ? 1 : 0;
}

// ---------------------------------------------------------------------------
// effWT[n][k] = w[k][n] + sum_r la[k][r]*lb[r][n]  (input dtype per flag, bf16 out)
// grid (D/64, D/64), block 256
__global__ __launch_bounds__(256) void prep_wt(const void* __restrict__ w_, const void* __restrict__ la_,
                                               const void* __restrict__ lb_, u16* __restrict__ wt,
                                               const int* __restrict__ flagp)
{
  const int f32i = *flagp;
  __shared__ float tile[64][65];
  const int tid = threadIdx.x;
  const int k0 = blockIdx.x*64, n0 = blockIdx.y*64;
  const int c  = tid & 63;
  const int r0 = (tid >> 6) * 16;
  float lbv[8];
  if (f32i){
    const float* lb = (const float*)lb_;
    #pragma unroll
    for (int r=0;r<8;++r) lbv[r] = lb[(size_t)r*D_ + n0 + c];
  } else {
    const u16* lb = (const u16*)lb_;
    #pragma unroll
    for (int r=0;r<8;++r) lbv[r] = b2f(lb[(size_t)r*D_ + n0 + c]);
  }
  #pragma unroll
  for (int kk=0;kk<16;++kk){
    const int k = k0 + r0 + kk;
    float val;
    if (f32i){
      const float* w32 = (const float*)w_;  const float* la = (const float*)la_;
      val = w32[(size_t)k*D_ + n0 + c];
      f32x4 a0 = *(const f32x4*)(la + k*8);
      f32x4 a1 = *(const f32x4*)(la + k*8 + 4);
      #pragma unroll
      for (int r=0;r<4;++r) val += a0[r]*lbv[r];
      #pragma unroll
      for (int r=0;r<4;++r) val += a1[r]*lbv[4+r];
    } else {
      const u16* w16 = (const u16*)w_;  const u16* la = (const u16*)la_;
      val = b2f(w16[(size_t)k*D_ + n0 + c]);
      s16x8 av = *(const s16x8*)(la + k*8);
      #pragma unroll
      for (int r=0;r<8;++r) val += b2f((u16)av[r])*lbv[r];
    }
    tile[r0+kk][c] = val;
  }
  __syncthreads();
  #pragma unroll
  for (int nn=0;nn<16;++nn){
    const int nr = r0 + nn;
    wt[(size_t)(n0+nr)*D_ + k0 + c] = f2b(tile[c][nr]);
  }
}

// ---------------------------------------------------------------------------
// VT[b][d][s] = V[b][s][d].  grid (S/64, D/64, B), block 256
__global__ __launch_bounds__(256) void transpose_v(const u16* __restrict__ V, u16* __restrict__ VT)
{
  __shared__ u16 tile[64][66];
  const int bz = blockIdx.z;
  const int s0 = blockIdx.x*64, d0 = blockIdx.y*64;
  const int tid = threadIdx.x;
  const u16* Vb = V + (size_t)bz*S_*D_;
  u16* VTb = VT + (size_t)bz*D_*S_;
  const int c = tid & 63, r0 = (tid>>6)*16;
  #pragma unroll
  for (int i=0;i<16;++i) tile[r0+i][c] = Vb[(size_t)(s0+r0+i)*D_ + d0 + c];
  __syncthreads();
  #pragma unroll
  for (int i=0;i<16;++i) VTb[(size_t)(d0+r0+i)*S_ + s0 + c] = tile[c][r0+i];
}

// ---------------------------------------------------------------------------
// C[m][n] = sum_k A[m][k]*BT[n][k] + bias[n].  M=4096, N=K=2048.
// aF: A dtype follows flag (else bf16).  oF: out dtype follows flag (else bf16).
// bias always follows flag.
__global__ __launch_bounds__(256) void gemm_bt(const void* __restrict__ A_, const u16* __restrict__ BT,
                                               const void* __restrict__ bias_, void* __restrict__ C_,
                                               const int* __restrict__ flagp, int aF, int oF)
{
  constexpr int N = D_, K = D_;
  const int f = *flagp;
  const bool a32 = (aF != 0) && (f != 0);
  const bool o32 = (oF != 0) && (f != 0);
  __shared__ u16 As[128*32];
  __shared__ u16 Bs[128*32];
  const int tid = threadIdx.x;
  const int w = tid>>6, lane = tid&63, g = lane>>4, lr = lane&15;
  const int wm = w>>1, wn = w&1;
  const int m0 = blockIdx.y*128, n0 = blockIdx.x*128;
  const int srow = lane>>2, scol = (lane&3)*8;     // staging: 16 rows x 32 cols per wave-call
  f32x4 acc[4][4] = {};
  for (int k0=0;k0<K;k0+=32){
    if (a32){
      const float* Af = (const float*)A_;
      #pragma unroll
      for (int j=0;j<2;++j){
        const int rb = j*64 + w*16;
        const float* src = Af + (size_t)(m0+rb+srow)*K + k0 + scol;
        f32x4 x0 = *(const f32x4*)src;
        f32x4 x1 = *(const f32x4*)(src + 4);
        s16x8 pk;
        #pragma unroll
        for (int i=0;i<4;++i){ pk[i] = (short)f2b(x0[i]); pk[4+i] = (short)f2b(x1[i]); }
        *(s16x8*)(As + (rb+srow)*32 + scol) = pk;
      }
    } else {
      const u16* Ab = (const u16*)A_;
      #pragma unroll
      for (int j=0;j<2;++j){
        const int rb = j*64 + w*16;
        glds16(Ab + (size_t)(m0+rb+srow)*K + k0 + scol, (void*)(As + rb*32));
      }
    }
    #pragma unroll
    for (int j=0;j<2;++j){
      const int rb = j*64 + w*16;
      glds16(BT + (size_t)(n0+rb+srow)*K + k0 + scol, (void*)(Bs + rb*32));
    }
    __syncthreads();
    s16x8 af[4], bfr[4];
    #pragma unroll
    for (int i=0;i<4;++i) af[i]  = *(const s16x8*)(As + (wm*64+i*16+lr)*32 + g*8);
    #pragma unroll
    for (int i=0;i<4;++i) bfr[i] = *(const s16x8*)(Bs + (wn*64+i*16+lr)*32 + g*8);
    #pragma unroll
    for (int mi=0;mi<4;++mi)
      #pragma unroll
      for (int ni=0;ni<4;++ni)
        acc[mi][ni] = __builtin_amdgcn_mfma_f32_16x16x32_bf16(af[mi], bfr[ni], acc[mi][ni], 0,0,0);
    __syncthreads();
  }
  #pragma unroll
  for (int ni=0;ni<4;++ni){
    const int n = n0 + wn*64 + ni*16 + lr;
    const float bv = f ? ((const float*)bias_)[n] : b2f(((const u16*)bias_)[n]);
    #pragma unroll
    for (int mi=0;mi<4;++mi){
      const int m = m0 + wm*64 + mi*16 + 4*g;
      #pragma unroll
      for (int r=0;r<4;++r){
        const float val = acc[mi][ni][r] + bv;
        if (o32) ((float*)C_)[(size_t)(m+r)*N + n] = val;
        else     ((u16*)C_)[(size_t)(m+r)*N + n] = f2b(val);
      }
    }
  }
}

// ---------------------------------------------------------------------------
// Causal flash attention.  grid (S/64, H, B), block 256 (4 waves x 16 q-rows).
// Q,K in [B,S,D] bf16 (head-interleaved), VT in [B,D,S] bf16, O out [B,S,D] bf16.
__global__ __launch_bounds__(256) void attn(const u16* __restrict__ Q, const u16* __restrict__ K,
                                            const u16* __restrict__ VT, u16* __restrict__ O)
{
  __shared__ u16  Pl[4][16][72];     // P[q][kv], padded: 144B row = 9x16B
  __shared__ float scl[4][16];       // per-q rescale factor / final sum
  __shared__ u16  Ol[4][16][136];    // O[q][d] staging, 272B row = 17x16B
  const int tid = threadIdx.x;
  const int w = tid>>6, lane = tid&63, g = lane>>4, lr = lane&15;
  const int h = blockIdx.y, bz = blockIdx.z;
  const int q0 = blockIdx.x*64 + w*16;             // this wave's first q row
  const u16* Qb  = Q  + (size_t)bz*S_*D_;
  const u16* Kb  = K  + (size_t)bz*S_*D_;
  const u16* VTb = VT + (size_t)bz*D_*S_;
  u16* Ob = O + (size_t)bz*S_*D_;

  // Q fragments, pre-scaled by 1/sqrt(dk)
  s16x8 qf[4];
  #pragma unroll
  for (int dc=0;dc<4;++dc){
    s16x8 t = *(const s16x8*)(Qb + (size_t)(q0+lr)*D_ + h*DK_ + dc*32 + g*8);
    #pragma unroll
    for (int i=0;i<8;++i) t[i] = (short)f2b(b2f((u16)t[i]) * SCALE_);
    qf[dc] = t;
  }
  float m_[4] = {-1e30f,-1e30f,-1e30f,-1e30f};
  float l_[4] = {0.f,0.f,0.f,0.f};
  f32x4 accO[8] = {};                // O^T[d=dt*16+4g+r][q=lr], fp32
  const int nt = blockIdx.x + 1;     // same for all 4 waves -> barriers legal
  for (int t=0;t<nt;++t){
    const int kv0 = t*64;
    const bool lastT = (t == nt-1);
    // --- QK^T: S[q=4g+r][key=kt*16+lr], accumulated over d ---
    f32x4 sacc[4] = {};
    #pragma unroll
    for (int dc=0;dc<4;++dc){
      #pragma unroll
      for (int kt=0;kt<4;++kt){
        s16x8 kf = *(const s16x8*)(Kb + (size_t)(kv0+kt*16+lr)*D_ + h*DK_ + dc*32 + g*8);
        sacc[kt] = __builtin_amdgcn_mfma_f32_16x16x32_bf16(qf[dc], kf, sacc[kt], 0,0,0);
      }
    }
    if (lastT){
      #pragma unroll
      for (int kt=0;kt<4;++kt)
        #pragma unroll
        for (int r=0;r<4;++r)
          if (kv0 + kt*16 + lr > q0 + 4*g + r) sacc[kt][r] = -1e30f;
    }
    // --- online softmax (row j=4g+r lives on 16-lane group g) ---
    #pragma unroll
    for (int r=0;r<4;++r){
      float tm = fmaxf(fmaxf(sacc[0][r],sacc[1][r]), fmaxf(sacc[2][r],sacc[3][r]));
      #pragma unroll
      for (int off=1;off<16;off<<=1) tm = fmaxf(tm, __shfl_xor(tm, off));
      const float mn = fmaxf(m_[r], tm);
      const float sc = __expf(m_[r] - mn);
      m_[r] = mn;
      float rs = 0.f;
      #pragma unroll
      for (int kt=0;kt<4;++kt){ float p = __expf(sacc[kt][r]-mn); sacc[kt][r]=p; rs += p; }
      #pragma unroll
      for (int off=1;off<16;off<<=1) rs += __shfl_xor(rs, off);
      l_[r] = l_[r]*sc + rs;
      if (lr == r) scl[w][4*g+r] = sc;
      #pragma unroll
      for (int kt=0;kt<4;++kt) Pl[w][4*g+r][kt*16+lr] = f2b(sacc[kt][r]);
    }
    __syncthreads();
    // --- PV: O^T = V^T @ P^T ---
    const float scc = scl[w][lr];
    #pragma unroll
    for (int dt=0;dt<8;++dt)
      #pragma unroll
      for (int r=0;r<4;++r) accO[dt][r] *= scc;
    const s16x8 pf0 = *(const s16x8*)(&Pl[w][lr][0]  + g*8);
    const s16x8 pf1 = *(const s16x8*)(&Pl[w][lr][32] + g*8);
    #pragma unroll
    for (int dt=0;dt<8;++dt){
      s16x8 vf0 = *(const s16x8*)(VTb + (size_t)(h*DK_+dt*16+lr)*S_ + kv0 + g*8);
      accO[dt] = __builtin_amdgcn_mfma_f32_16x16x32_bf16(vf0, pf0, accO[dt], 0,0,0);
      s16x8 vf1 = *(const s16x8*)(VTb + (size_t)(h*DK_+dt*16+lr)*S_ + kv0 + 32 + g*8);
      accO[dt] = __builtin_amdgcn_mfma_f32_16x16x32_bf16(vf1, pf1, accO[dt], 0,0,0);
    }
    __syncthreads();
  }
  // --- finalize: 1/l, transpose via LDS, coalesced store ---
  #pragma unroll
  for (int r=0;r<4;++r) if (lr == r) scl[w][4*g+r] = l_[r];
  __syncthreads();
  const float linv = 1.0f / scl[w][lr];
  #pragma unroll
  for (int dt=0;dt<8;++dt)
    #pragma unroll
    for (int r=0;r<4;++r)
      Ol[w][lr][dt*16 + 4*g + r] = f2b(accO[dt][r] * linv);
  __syncthreads();
  #pragma unroll
  for (int p=0;p<4;++p){
    const int ql = p*4 + g;
    s16x8 ov = *(const s16x8*)(&Ol[w][ql][0] + lr*8);
    *(s16x8*)(Ob + (size_t)(q0+ql)*D_ + h*DK_ + lr*8) = ov;
  }
}

// ---------------------------------------------------------------------------
extern "C" void kernel_launch(void* const* d_in, const int* in_sizes, int n_in,
                              void* d_out, int out_size, void* d_ws, size_t ws_size,
                              hipStream_t stream)
{
  const void* q   = d_in[0];
  const void* k   = d_in[1];
  const void* v   = d_in[2];
  const void* wq  = d_in[3];  const void* bq = d_in[4];
  const void* laq = d_in[5];  const void* lbq= d_in[6];
  const void* wk  = d_in[7];  const void* bk = d_in[8];
  const void* lak = d_in[9];  const void* lbk= d_in[10];
  const void* wv  = d_in[11]; const void* bv = d_in[12];
  const void* lav = d_in[13]; const void* lbv= d_in[14];
  const void* wo  = d_in[15]; const void* bo = d_in[16];
  const void* lao = d_in[17]; const void* lbo= d_in[18];

  char* ws = (char*)d_ws;
  int* flag = (int*)ws;
  char* base = ws + 256;
  const size_t MB = 1u<<20;
  u16* W   = (u16*)(base);            //  8 MiB, reused for each effW^T
  u16* Qb  = (u16*)(base +  8*MB);    // 16 MiB
  u16* Kb  = (u16*)(base + 24*MB);    // 16 MiB
  u16* Vb  = (u16*)(base + 40*MB);    // 16 MiB
  u16* VTb = (u16*)(base + 56*MB);    // 16 MiB  -> total 72 MiB + 256 B
  u16* Ob  = Vb;                      // V dead after transpose

  dim3 blk(256);
  dim3 gW(D_/64, D_/64);
  dim3 gG(D_/128, MROWS/128);
  detect32<<<1, blk, 0, stream>>>((const unsigned*)q, flag);
  prep_wt<<<gW, blk, 0, stream>>>(wq, laq, lbq, W, flag);
  gemm_bt<<<gG, blk, 0, stream>>>(q, W, bq, Qb, flag, 1, 0);
  prep_wt<<<gW, blk, 0, stream>>>(wk, lak, lbk, W, flag);
  gemm_bt<<<gG, blk, 0, stream>>>(k, W, bk, Kb, flag, 1, 0);
  prep_wt<<<gW, blk, 0, stream>>>(wv, lav, lbv, W, flag);
  gemm_bt<<<gG, blk, 0, stream>>>(v, W, bv, Vb, flag, 1, 0);
  transpose_v<<<dim3(S_/64, D_/64, B_), blk, 0, stream>>>(Vb, VTb);
  attn<<<dim3(S_/64, H_, B_), blk, 0, stream>>>(Qb, Kb, VTb, Ob);
  prep_wt<<<gW, blk, 0, stream>>>(wo, lao, lbo, W, flag);
  gemm_bt<<<gG, blk, 0, stream>>>(Ob, W, bo, d_out, flag, 0, 1);
}

// Round 3
// 560.360 us; speedup vs baseline: 1.8088x; 1.8088x over previous
//
#include <hip/hip_runtime.h>

// LoRA multi-head attention forward, B=2 S=2048 D=2048 H=16 dk=128 rank=8.
// Device dtype auto-detected (bf16 vs fp32) -> flag in ws; internal compute bf16.
// Pipeline: detect -> [prep effW^T -> GEMM] x3 (Q,K,V) -> V transpose ->
// causal flash attention (LDS-staged, double-buffered KV) -> prep effWo^T -> output GEMM.

#define B_   2
#define S_   2048
#define D_   2048
#define H_   16
#define DK_  128
#define MROWS (B_*S_)            // 4096
#define SCALE_ 0.08838834764831845f   // 1/sqrt(128)

using f32x4 = __attribute__((ext_vector_type(4))) float;
using s16x8 = __attribute__((ext_vector_type(8))) short;
typedef unsigned short u16;

__device__ __forceinline__ float b2f(u16 u){ union{unsigned u32; float f;} x; x.u32=((unsigned)u)<<16; return x.f; }
__device__ __forceinline__ u16 f2b(float f){ union{float f; unsigned u;} x; x.f=f; unsigned r=x.u+0x7fffu+((x.u>>16)&1u); return (u16)(r>>16); }

__device__ __forceinline__ void glds16(const void* g, void* l){
  __builtin_amdgcn_global_load_lds((const __attribute__((address_space(1))) unsigned int*)g,
                                   (__attribute__((address_space(3))) unsigned int*)l, 16, 0, 0);
}

// ---------------------------------------------------------------------------
__global__ void detect32(const unsigned* __restrict__ q, int* __restrict__ flag)
{
  __shared__ int s[4];
  int c = 0;
  for (int i = threadIdx.x; i < 4096; i += 256){
    unsigned u = q[i];
    unsigned e0 = (u >> 7) & 0xFFu;
    if (e0 >= 0x90u) ++c;
  }
  #pragma unroll
  for (int off = 32; off; off >>= 1) c += __shfl_down(c, off);
  if ((threadIdx.x & 63) == 0) s[threadIdx.x >> 6] = c;
  __syncthreads();
  if (threadIdx.x == 0) *flag = ((s[0]+s[1]+s[2]+s[3]) > 64) ? 1 : 0;
}

// ---------------------------------------------------------------------------
// effWT[n][k] = w[k][n] + sum_r la[k][r]*lb[r][n]
__global__ __launch_bounds__(256) void prep_wt(const void* __restrict__ w_, const void* __restrict__ la_,
                                               const void* __restrict__ lb_, u16* __restrict__ wt,
                                               const int* __restrict__ flagp)
{
  const int f32i = *flagp;
  __shared__ float tile[64][65];
  const int tid = threadIdx.x;
  const int k0 = blockIdx.x*64, n0 = blockIdx.y*64;
  const int c  = tid & 63;
  const int r0 = (tid >> 6) * 16;
  float lbv[8];
  if (f32i){
    const float* lb = (const float*)lb_;
    #pragma unroll
    for (int r=0;r<8;++r) lbv[r] = lb[(size_t)r*D_ + n0 + c];
  } else {
    const u16* lb = (const u16*)lb_;
    #pragma unroll
    for (int r=0;r<8;++r) lbv[r] = b2f(lb[(size_t)r*D_ + n0 + c]);
  }
  #pragma unroll
  for (int kk=0;kk<16;++kk){
    const int k = k0 + r0 + kk;
    float val;
    if (f32i){
      const float* w32 = (const float*)w_;  const float* la = (const float*)la_;
      val = w32[(size_t)k*D_ + n0 + c];
      f32x4 a0 = *(const f32x4*)(la + k*8);
      f32x4 a1 = *(const f32x4*)(la + k*8 + 4);
      #pragma unroll
      for (int r=0;r<4;++r) val += a0[r]*lbv[r];
      #pragma unroll
      for (int r=0;r<4;++r) val += a1[r]*lbv[4+r];
    } else {
      const u16* w16 = (const u16*)w_;  const u16* la = (const u16*)la_;
      val = b2f(w16[(size_t)k*D_ + n0 + c]);
      s16x8 av = *(const s16x8*)(la + k*8);
      #pragma unroll
      for (int r=0;r<8;++r) val += b2f((u16)av[r])*lbv[r];
    }
    tile[r0+kk][c] = val;
  }
  __syncthreads();
  #pragma unroll
  for (int nn=0;nn<16;++nn){
    const int nr = r0 + nn;
    wt[(size_t)(n0+nr)*D_ + k0 + c] = f2b(tile[c][nr]);
  }
}

// ---------------------------------------------------------------------------
__global__ __launch_bounds__(256) void transpose_v(const u16* __restrict__ V, u16* __restrict__ VT)
{
  __shared__ u16 tile[64][66];
  const int bz = blockIdx.z;
  const int s0 = blockIdx.x*64, d0 = blockIdx.y*64;
  const int tid = threadIdx.x;
  const u16* Vb = V + (size_t)bz*S_*D_;
  u16* VTb = VT + (size_t)bz*D_*S_;
  const int c = tid & 63, r0 = (tid>>6)*16;
  #pragma unroll
  for (int i=0;i<16;++i) tile[r0+i][c] = Vb[(size_t)(s0+r0+i)*D_ + d0 + c];
  __syncthreads();
  #pragma unroll
  for (int i=0;i<16;++i) VTb[(size_t)(d0+r0+i)*S_ + s0 + c] = tile[c][r0+i];
}

// ---------------------------------------------------------------------------
// C[m][n] = sum_k A[m][k]*BT[n][k] + bias[n].  M=4096, N=K=2048.
__global__ __launch_bounds__(256) void gemm_bt(const void* __restrict__ A_, const u16* __restrict__ BT,
                                               const void* __restrict__ bias_, void* __restrict__ C_,
                                               const int* __restrict__ flagp, int aF, int oF)
{
  constexpr int N = D_, K = D_;
  const int f = *flagp;
  const bool a32 = (aF != 0) && (f != 0);
  const bool o32 = (oF != 0) && (f != 0);
  __shared__ u16 As[128*32];
  __shared__ u16 Bs[128*32];
  const int tid = threadIdx.x;
  const int w = tid>>6, lane = tid&63, g = lane>>4, lr = lane&15;
  const int wm = w>>1, wn = w&1;
  const int m0 = blockIdx.y*128, n0 = blockIdx.x*128;
  const int srow = lane>>2, scol = (lane&3)*8;
  f32x4 acc[4][4] = {};
  for (int k0=0;k0<K;k0+=32){
    if (a32){
      const float* Af = (const float*)A_;
      #pragma unroll
      for (int j=0;j<2;++j){
        const int rb = j*64 + w*16;
        const float* src = Af + (size_t)(m0+rb+srow)*K + k0 + scol;
        f32x4 x0 = *(const f32x4*)src;
        f32x4 x1 = *(const f32x4*)(src + 4);
        s16x8 pk;
        #pragma unroll
        for (int i=0;i<4;++i){ pk[i] = (short)f2b(x0[i]); pk[4+i] = (short)f2b(x1[i]); }
        *(s16x8*)(As + (rb+srow)*32 + scol) = pk;
      }
    } else {
      const u16* Ab = (const u16*)A_;
      #pragma unroll
      for (int j=0;j<2;++j){
        const int rb = j*64 + w*16;
        glds16(Ab + (size_t)(m0+rb+srow)*K + k0 + scol, (void*)(As + rb*32));
      }
    }
    #pragma unroll
    for (int j=0;j<2;++j){
      const int rb = j*64 + w*16;
      glds16(BT + (size_t)(n0+rb+srow)*K + k0 + scol, (void*)(Bs + rb*32));
    }
    __syncthreads();
    s16x8 af[4], bfr[4];
    #pragma unroll
    for (int i=0;i<4;++i) af[i]  = *(const s16x8*)(As + (wm*64+i*16+lr)*32 + g*8);
    #pragma unroll
    for (int i=0;i<4;++i) bfr[i] = *(const s16x8*)(Bs + (wn*64+i*16+lr)*32 + g*8);
    #pragma unroll
    for (int mi=0;mi<4;++mi)
      #pragma unroll
      for (int ni=0;ni<4;++ni)
        acc[mi][ni] = __builtin_amdgcn_mfma_f32_16x16x32_bf16(af[mi], bfr[ni], acc[mi][ni], 0,0,0);
    __syncthreads();
  }
  #pragma unroll
  for (int ni=0;ni<4;++ni){
    const int n = n0 + wn*64 + ni*16 + lr;
    const float bv = f ? ((const float*)bias_)[n] : b2f(((const u16*)bias_)[n]);
    #pragma unroll
    for (int mi=0;mi<4;++mi){
      const int m = m0 + wm*64 + mi*16 + 4*g;
      #pragma unroll
      for (int r=0;r<4;++r){
        const float val = acc[mi][ni][r] + bv;
        if (o32) ((float*)C_)[(size_t)(m+r)*N + n] = val;
        else     ((u16*)C_)[(size_t)(m+r)*N + n] = f2b(val);
      }
    }
  }
}

// ---------------------------------------------------------------------------
// Causal flash attention.  grid (S/64, H, B), block 256 (4 waves x 16 q-rows).
// KV tiles staged in LDS (double-buffered, XOR-swizzled), coalesced glds16.
// q-tile order reversed so longest blocks start first.
__global__ __launch_bounds__(256) void attn(const u16* __restrict__ Q, const u16* __restrict__ K,
                                            const u16* __restrict__ VT, u16* __restrict__ O)
{
  __shared__ u16  Ks[2][64*128];     // 32 KB, rows kv (256B), swizzled
  __shared__ u16  Vs[2][128*64];     // 32 KB, rows d (128B), swizzled
  __shared__ u16  Pl[4][16][72];     // 9216 B, per-wave P[q][kv]
  __shared__ float scl[4][16];       // 256 B
  u16 (*Ol)[16][136] = (u16(*)[16][136])(&Ks[0][0]);   // 17408 B alias, dead staging

  const int tid = threadIdx.x;
  const int w = tid>>6, lane = tid&63, g = lane>>4, lr = lane&15;
  const int h = blockIdx.y, bz = blockIdx.z;
  const int qt = (int)(gridDim.x - 1u - blockIdx.x);   // reversed: long blocks first
  const int q0 = qt*64 + w*16;
  const u16* Qb  = Q  + (size_t)bz*S_*D_;
  const u16* Kb  = K  + (size_t)bz*S_*D_;
  const u16* VTb = VT + (size_t)bz*D_*S_;
  u16* Ob = O + (size_t)bz*S_*D_;
  const int nt = qt + 1;
  const int sw = (lr&7)<<4;                 // read-side swizzle (bytes)
  const int krow_l = lane>>4, kcol_l = (lane&15)*16;   // K staging lane map (4 rows/call)
  const int vrow_l = lane>>3, vcol_l = (lane&7)*16;    // V staging lane map (8 rows/call)

  // Q fragments, pre-scaled by 1/sqrt(dk)
  s16x8 qf[4];
  #pragma unroll
  for (int dc=0;dc<4;++dc){
    s16x8 t = *(const s16x8*)(Qb + (size_t)(q0+lr)*D_ + h*DK_ + dc*32 + g*8);
    #pragma unroll
    for (int i=0;i<8;++i) t[i] = (short)f2b(b2f((u16)t[i]) * SCALE_);
    qf[dc] = t;
  }

  // staging: per wave 4 K-calls + 4 V-calls, 1KB each, inverse-swizzled source
  #define STAGE_K(buf, t_) { const int kv0s = (t_)*64;                              \
    _Pragma("unroll")                                                               \
    for (int jj=0;jj<4;++jj){ const int j = w*4 + jj; const int r = j*4 + krow_l;   \
      const int cb = kcol_l ^ ((r&7)<<4);                                           \
      glds16(Kb + (size_t)(kv0s + r)*D_ + h*DK_ + (cb>>1), (void*)(&Ks[buf][0] + j*512)); } }
  #define STAGE_V(buf, t_) { const int kv0s = (t_)*64;                              \
    _Pragma("unroll")                                                               \
    for (int jj=0;jj<4;++jj){ const int j = w*4 + jj; const int r = j*8 + vrow_l;   \
      const int cb = vcol_l ^ ((r&7)<<4);                                           \
      glds16(VTb + (size_t)(h*DK_ + r)*S_ + kv0s + (cb>>1), (void*)(&Vs[buf][0] + j*512)); } }

  float m_[4] = {-1e30f,-1e30f,-1e30f,-1e30f};
  float l_[4] = {0.f,0.f,0.f,0.f};
  f32x4 accO[8] = {};                // O^T[d=dt*16+4g+r][q=lr], fp32

  STAGE_K(0, 0); STAGE_V(0, 0);
  __syncthreads();
  int cur = 0;
  for (int t=0;t<nt;++t){
    const int kv0 = t*64;
    const bool lastT = (t == nt-1);
    if (!lastT){ STAGE_K(cur^1, t+1); STAGE_V(cur^1, t+1); }
    // --- QK^T from LDS: S[q=4g+r][key=kt*16+lr] ---
    const u16* Ksc = &Ks[cur][0];
    f32x4 sacc[4] = {};
    #pragma unroll
    for (int dc=0;dc<4;++dc){
      const int cb = (dc*64 + g*16) ^ sw;
      #pragma unroll
      for (int kt=0;kt<4;++kt){
        s16x8 kf = *(const s16x8*)(Ksc + (kt*16+lr)*128 + (cb>>1));
        sacc[kt] = __builtin_amdgcn_mfma_f32_16x16x32_bf16(qf[dc], kf, sacc[kt], 0,0,0);
      }
    }
    if (lastT){
      #pragma unroll
      for (int kt=0;kt<4;++kt)
        #pragma unroll
        for (int r=0;r<4;++r)
          if (kv0 + kt*16 + lr > q0 + 4*g + r) sacc[kt][r] = -1e30f;
    }
    // --- online softmax (row j=4g+r lives on 16-lane group g; per-wave LDS only) ---
    #pragma unroll
    for (int r=0;r<4;++r){
      float tm = fmaxf(fmaxf(sacc[0][r],sacc[1][r]), fmaxf(sacc[2][r],sacc[3][r]));
      #pragma unroll
      for (int off=1;off<16;off<<=1) tm = fmaxf(tm, __shfl_xor(tm, off));
      const float mn = fmaxf(m_[r], tm);
      const float sc = __expf(m_[r] - mn);
      m_[r] = mn;
      float rs = 0.f;
      #pragma unroll
      for (int kt=0;kt<4;++kt){ float p = __expf(sacc[kt][r]-mn); sacc[kt][r]=p; rs += p; }
      #pragma unroll
      for (int off=1;off<16;off<<=1) rs += __shfl_xor(rs, off);
      l_[r] = l_[r]*sc + rs;
      if (lr == r) scl[w][4*g+r] = sc;
      #pragma unroll
      for (int kt=0;kt<4;++kt) Pl[w][4*g+r][kt*16+lr] = f2b(sacc[kt][r]);
    }
    // --- PV from LDS: O^T += V^T @ P^T (intra-wave lgkm ordering, no barrier) ---
    const float scc = scl[w][lr];
    #pragma unroll
    for (int dt=0;dt<8;++dt)
      #pragma unroll
      for (int r=0;r<4;++r) accO[dt][r] *= scc;
    const s16x8 pf0 = *(const s16x8*)(&Pl[w][lr][0]  + g*8);
    const s16x8 pf1 = *(const s16x8*)(&Pl[w][lr][32] + g*8);
    const u16* Vsc = &Vs[cur][0];
    const int cb0 = (g*16) ^ sw;
    const int cb1 = (64 + g*16) ^ sw;
    #pragma unroll
    for (int dt=0;dt<8;++dt){
      s16x8 vf0 = *(const s16x8*)(Vsc + (dt*16+lr)*64 + (cb0>>1));
      accO[dt] = __builtin_amdgcn_mfma_f32_16x16x32_bf16(vf0, pf0, accO[dt], 0,0,0);
      s16x8 vf1 = *(const s16x8*)(Vsc + (dt*16+lr)*64 + (cb1>>1));
      accO[dt] = __builtin_amdgcn_mfma_f32_16x16x32_bf16(vf1, pf1, accO[dt], 0,0,0);
    }
    __syncthreads();          // staged t+1 visible; buffers swappable
    cur ^= 1;
  }
  // --- finalize: 1/l, transpose via LDS (aliases dead K staging), store ---
  #pragma unroll
  for (int r=0;r<4;++r) if (lr == r) scl[w][4*g+r] = l_[r];
  __syncthreads();
  const float linv = 1.0f / scl[w][lr];
  #pragma unroll
  for (int dt=0;dt<8;++dt)
    #pragma unroll
    for (int r=0;r<4;++r)
      Ol[w][lr][dt*16 + 4*g + r] = f2b(accO[dt][r] * linv);
  __syncthreads();
  #pragma unroll
  for (int p=0;p<4;++p){
    const int ql = p*4 + g;
    s16x8 ov = *(const s16x8*)(&Ol[w][ql][0] + lr*8);
    *(s16x8*)(Ob + (size_t)(q0+ql)*D_ + h*DK_ + lr*8) = ov;
  }
  #undef STAGE_K
  #undef STAGE_V
}

// ---------------------------------------------------------------------------
extern "C" void kernel_launch(void* const* d_in, const int* in_sizes, int n_in,
                              void* d_out, int out_size, void* d_ws, size_t ws_size,
                              hipStream_t stream)
{
  const void* q   = d_in[0];
  const void* k   = d_in[1];
  const void* v   = d_in[2];
  const void* wq  = d_in[3];  const void* bq = d_in[4];
  const void* laq = d_in[5];  const void* lbq= d_in[6];
  const void* wk  = d_in[7];  const void* bk = d_in[8];
  const void* lak = d_in[9];  const void* lbk= d_in[10];
  const void* wv  = d_in[11]; const void* bv = d_in[12];
  const void* lav = d_in[13]; const void* lbv= d_in[14];
  const void* wo  = d_in[15]; const void* bo = d_in[16];
  const void* lao = d_in[17]; const void* lbo= d_in[18];

  char* ws = (char*)d_ws;
  int* flag = (int*)ws;
  char* base = ws + 256;
  const size_t MB = 1u<<20;
  u16* W   = (u16*)(base);            //  8 MiB, reused for each effW^T
  u16* Qb  = (u16*)(base +  8*MB);    // 16 MiB
  u16* Kb  = (u16*)(base + 24*MB);    // 16 MiB
  u16* Vb  = (u16*)(base + 40*MB);    // 16 MiB
  u16* VTb = (u16*)(base + 56*MB);    // 16 MiB  -> total 72 MiB + 256 B
  u16* Ob  = Vb;                      // V dead after transpose

  dim3 blk(256);
  dim3 gW(D_/64, D_/64);
  dim3 gG(D_/128, MROWS/128);
  detect32<<<1, blk, 0, stream>>>((const unsigned*)q, flag);
  prep_wt<<<gW, blk, 0, stream>>>(wq, laq, lbq, W, flag);
  gemm_bt<<<gG, blk, 0, stream>>>(q, W, bq, Qb, flag, 1, 0);
  prep_wt<<<gW, blk, 0, stream>>>(wk, lak, lbk, W, flag);
  gemm_bt<<<gG, blk, 0, stream>>>(k, W, bk, Kb, flag, 1, 0);
  prep_wt<<<gW, blk, 0, stream>>>(wv, lav, lbv, W, flag);
  gemm_bt<<<gG, blk, 0, stream>>>(v, W, bv, Vb, flag, 1, 0);
  transpose_v<<<dim3(S_/64, D_/64, B_), blk, 0, stream>>>(Vb, VTb);
  attn<<<dim3(S_/64, H_, B_), blk, 0, stream>>>(Qb, Kb, VTb, Ob);
  prep_wt<<<gW, blk, 0, stream>>>(wo, lao, lbo, W, flag);
  gemm_bt<<<gG, blk, 0, stream>>>(Ob, W, bo, d_out, flag, 0, 1);
}